// Round 6
// baseline (1017.278 us; speedup 1.0000x reference)
//
#include <hip/hip_runtime.h>
#include <stdint.h>

// ---------------------------------------------------------------------------
// SpatialGNN forward, round 6.
// R5: 925us. k_group issue-limited (Occ 21%: single-wave workgroups; 7-op
// inner chain). ~350us in small kernels + launch gaps (42 dispatches).
// R6: (1) k_group: 4 nodes/256-thr block, T pre-unpacked to 128 VGPR f32,
//     dual accumulators. (2) fuse xc+GRU+xb2+agg0 -> k_xcgru; xb2 into
//     k_lift; raw-input decode into consumers. (3) Set2Set: batch is SORTED
//     -> one kernel (block=graph, binary search, LDS softmax) incl. out head.
// 22 dispatches total.
// ---------------------------------------------------------------------------

#define NN 10000
#define EE 50000
#define BBG 512

typedef __attribute__((ext_vector_type(8))) short short8;
typedef __attribute__((ext_vector_type(4))) float f32x4;
typedef __attribute__((ext_vector_type(2))) float f32x2;

__device__ __forceinline__ float b2f(unsigned short u) {
  return __uint_as_float(((unsigned)u) << 16);
}
__device__ __forceinline__ float b2f_lo(unsigned u) { return __uint_as_float(u << 16); }
__device__ __forceinline__ float b2f_hi(unsigned u) { return __uint_as_float(u & 0xFFFF0000u); }
__device__ __forceinline__ unsigned short f2b(float f) {
  unsigned u = __float_as_uint(f);
  u += 0x7FFFu + ((u >> 16) & 1u);  // RNE
  return (unsigned short)(u >> 16);
}
__device__ __forceinline__ float sigm(float x) { return 1.0f / (1.0f + __expf(-x)); }
__device__ __forceinline__ float siluf(float x) { return x / (1.0f + __expf(-x)); }
__device__ __forceinline__ unsigned encf(float f) {
  unsigned u = __float_as_uint(f);
  return (u & 0x80000000u) ? ~u : (u | 0x80000000u);
}
__device__ __forceinline__ float rawf(const void* p, int f, int i) {
  return f ? b2f(((const unsigned short*)p)[i]) : ((const float*)p)[i];
}

// ---------------- dtype detection on edge_attr (uniform[0,1)) --------------
__global__ __launch_bounds__(256) void k_detect(const unsigned* __restrict__ w,
                                                int* __restrict__ flag) {
  __shared__ int cnt;
  if (threadIdx.x == 0) cnt = 0;
  __syncthreads();
  int c = 0;
  for (int i = threadIdx.x; i < 4096; i += 256) {
    unsigned lo = w[i] & 0xFFFFu;
    if (lo - 0x3A00u < 0x600u) c++;
  }
  atomicAdd(&cnt, c);
  __syncthreads();
  if (threadIdx.x == 0) *flag = (cnt > 2048) ? 1 : 0;  // 1 = inputs are bf16
}

// ---------------- convert weight inputs to canonical fp32 ------------------
#define NCVT 20
struct Cvt {
  const void* src[NCVT];
  float* dst[NCVT];
  int n[NCVT];
};

__global__ __launch_bounds__(256) void k_convert(Cvt c, const int* __restrict__ flag) {
  const int f = *flag;
  const int stride = gridDim.x * blockDim.x;
  const int tid = blockIdx.x * blockDim.x + threadIdx.x;
#pragma unroll 1
  for (int a = 0; a < NCVT; a++) {
    const int n = c.n[a];
    const float* sf = (const float*)c.src[a];
    const unsigned short* sb = (const unsigned short*)c.src[a];
    float* d = c.dst[a];
    for (int i = tid; i < n; i += stride) d[i] = f ? b2f(sb[i]) : sf[i];
  }
}

// ---------------- CSR by src + dst degree histogram ------------------------
__global__ __launch_bounds__(256) void k_hist(const int* __restrict__ ei,
                                              int* __restrict__ cnt,
                                              int* __restrict__ cntd) {
  int e = blockIdx.x * 256 + threadIdx.x;
  if (e < EE) {
    atomicAdd(cnt + ei[e], 1);
    atomicAdd(cntd + ei[EE + e], 1);
  }
}

__global__ __launch_bounds__(256) void k_scan(const int* __restrict__ cnt,
                                              const int* __restrict__ cntd,
                                              int* __restrict__ eptr,
                                              int* __restrict__ cursor,
                                              float* __restrict__ invd) {
  __shared__ int part[256];
  const int t = threadIdx.x;
  const int c0 = t * 40;
  int s = 0;
  for (int i = 0; i < 40; i++) {
    int idx = c0 + i;
    if (idx < NN) s += cnt[idx];
  }
  part[t] = s;
  __syncthreads();
  if (t == 0) {
    int run = 0;
    for (int i = 0; i < 256; i++) { int v = part[i]; part[i] = run; run += v; }
  }
  __syncthreads();
  int run = part[t];
  for (int i = 0; i < 40; i++) {
    int idx = c0 + i;
    if (idx < NN) {
      eptr[idx] = run;
      cursor[idx] = run;
      run += cnt[idx];
      invd[idx] = 1.0f / fmaxf((float)cntd[idx], 1.0f);
    }
  }
  if (t == 255) eptr[NN] = EE;
}

__global__ __launch_bounds__(256) void k_scatter(const int* __restrict__ ei,
                                                 int* __restrict__ cursor,
                                                 int* __restrict__ eord) {
  int e = blockIdx.x * 256 + threadIdx.x;
  if (e < EE) {
    int pos = atomicAdd(cursor + ei[e], 1);
    eord[pos] = e;
  }
}

// -------- lift: x = silu(x_in@flW.T+flb); also xb, xb2, agg=0 --------------
__global__ __launch_bounds__(256) void k_lift(const void* __restrict__ xin,
                                              const float* __restrict__ flW,
                                              const float* __restrict__ flb,
                                              const float* __restrict__ b2,
                                              float* __restrict__ x,
                                              unsigned short* __restrict__ xb,
                                              float* __restrict__ xb2,
                                              float* __restrict__ agg,
                                              const int* __restrict__ flag) {
  const int f = *flag;
  int node = blockIdx.x * 4 + (threadIdx.x >> 6);
  int h = threadIdx.x & 63;
  float acc = flb[h];
#pragma unroll
  for (int c = 0; c < 11; c++)
    acc += rawf(xin, f, node * 11 + c) * flW[h * 11 + c];
  float v = siluf(acc);
  x[node * 64 + h] = v;
  xb[node * 64 + h] = f2b(v);
  // xb2 via readlane broadcast of this node's x
  int xvi = __float_as_int(v);
  float a2 = 0.0f;
#pragma unroll 8
  for (int i = 0; i < 64; i++) {
    float xi = __int_as_float(__builtin_amdgcn_readlane(xvi, i));
    a2 += xi * b2[i * 64 + h];
  }
  xb2[node * 64 + h] = a2;
  agg[(size_t)node * 64 + h] = 0.0f;
}

// ---------- s[e,k] = silu(ef @ nn_W1.T + nn_b1) bf16 -----------------------
__global__ __launch_bounds__(256) void k_sdeg(const void* __restrict__ ea,
                                              const void* __restrict__ pos,
                                              const int* __restrict__ ei,
                                              const float* __restrict__ W1,
                                              const float* __restrict__ b1,
                                              unsigned short* __restrict__ s_bf,
                                              const int* __restrict__ flag) {
  const int f = *flag;
  int e = blockIdx.x * 2 + (threadIdx.x >> 7);
  int k = threadIdx.x & 127;
  int src = ei[e], dst = ei[EE + e];
  float dx = rawf(pos, f, src * 3 + 0) - rawf(pos, f, dst * 3 + 0);
  float dy = rawf(pos, f, src * 3 + 1) - rawf(pos, f, dst * 3 + 1);
  float dz = rawf(pos, f, src * 3 + 2) - rawf(pos, f, dst * 3 + 2);
  float dist = sqrtf(dx * dx + dy * dy + dz * dz);
  float acc = b1[k];
  acc += rawf(ea, f, e * 4 + 0) * W1[k * 5 + 0];
  acc += rawf(ea, f, e * 4 + 1) * W1[k * 5 + 1];
  acc += rawf(ea, f, e * 4 + 2) * W1[k * 5 + 2];
  acc += rawf(ea, f, e * 4 + 3) * W1[k * 5 + 3];
  acc += dist * W1[k * 5 + 4];
  s_bf[e * 128 + k] = f2b(siluf(acc));
}

// ---- W2t[(o*128+k)*64 + i] = bf16(W2[(i*64+o)*128 + k]) -------------------
__global__ __launch_bounds__(256) void k_w2t(const float* __restrict__ W2,
                                             unsigned short* __restrict__ W2t) {
  int j = blockIdx.x * 256 + threadIdx.x;
  int i = j & 63;
  int k = (j >> 6) & 127;
  int o = j >> 13;
  W2t[j] = f2b(W2[(size_t)(i * 64 + o) * 128 + k]);
}

// ---- T GEMM with LDS-staged coalesced epilogue ----------------------------
template <int KC>
__global__ __launch_bounds__(256) void k_T(const unsigned short* __restrict__ xb,
                                           const unsigned short* __restrict__ W2t,
                                           unsigned short* __restrict__ Tc, int K0) {
  __shared__ unsigned short sh[2 * 128 * 72];
  unsigned short* As = sh;
  unsigned short* Bs = sh + 128 * 72;
  const int t = threadIdx.x;
  const int n0 = blockIdx.x * 128;
  const int c0 = blockIdx.y * 128;
  const int lane = t & 63;
  const int w = t >> 6;
  const int lm = lane & 15;
  const int quad = lane >> 4;
  const int wm = w & 1;
  const int wn = w >> 1;

  for (int p = t; p < 128 * 8; p += 256) {
    int r = p >> 3, cc = (p & 7) * 8;
    uint4 v = make_uint4(0u, 0u, 0u, 0u);
    if (n0 + r < NN) v = *reinterpret_cast<const uint4*>(xb + (size_t)(n0 + r) * 64 + cc);
    *reinterpret_cast<uint4*>(&As[r * 72 + cc]) = v;
  }
  for (int p = t; p < 128 * 8; p += 256) {
    int r = p >> 3, cc = (p & 7) * 8;
    int c = c0 + r;
    int o = c / KC;
    int kg = K0 + (c % KC);
    uint4 v = *reinterpret_cast<const uint4*>(W2t + (size_t)(o * 128 + kg) * 64 + cc);
    *reinterpret_cast<uint4*>(&Bs[r * 72 + cc]) = v;
  }
  __syncthreads();

  f32x4 acc[4][4];
#pragma unroll
  for (int mt = 0; mt < 4; mt++)
#pragma unroll
    for (int nt = 0; nt < 4; nt++) acc[mt][nt] = (f32x4)(0.0f);

#pragma unroll
  for (int ks = 0; ks < 2; ks++) {
    const int kk = ks * 32 + quad * 8;
    short8 af[4], bfr[4];
#pragma unroll
    for (int mt = 0; mt < 4; mt++)
      af[mt] = *reinterpret_cast<const short8*>(&As[(wm * 64 + mt * 16 + lm) * 72 + kk]);
#pragma unroll
    for (int nt = 0; nt < 4; nt++)
      bfr[nt] = *reinterpret_cast<const short8*>(&Bs[(wn * 64 + nt * 16 + lm) * 72 + kk]);
#pragma unroll
    for (int mt = 0; mt < 4; mt++)
#pragma unroll
      for (int nt = 0; nt < 4; nt++)
        acc[mt][nt] = __builtin_amdgcn_mfma_f32_16x16x32_bf16(af[mt], bfr[nt], acc[mt][nt], 0, 0, 0);
  }

  __syncthreads();
  unsigned short* st = sh;  // 128*132 <= 18432 shorts
#pragma unroll
  for (int nt = 0; nt < 4; nt++) {
    int col = wn * 64 + nt * 16 + lm;
#pragma unroll
    for (int mt = 0; mt < 4; mt++) {
#pragma unroll
      for (int reg = 0; reg < 4; reg++) {
        int row = wm * 64 + mt * 16 + quad * 4 + reg;
        st[row * 132 + col] = f2b(acc[mt][nt][reg]);
      }
    }
  }
  __syncthreads();
  const int r16 = t >> 4;
  const int c8 = (t & 15) * 8;
#pragma unroll
  for (int it = 0; it < 8; it++) {
    int row = it * 16 + r16;
    int n = n0 + row;
    if (n < NN) {
      uint2 v0 = *reinterpret_cast<const uint2*>(&st[row * 132 + c8]);
      uint2 v1 = *reinterpret_cast<const uint2*>(&st[row * 132 + c8 + 4]);
      uint4 v = make_uint4(v0.x, v0.y, v1.x, v1.y);
      *reinterpret_cast<uint4*>(Tc + (size_t)n * (64 * KC) + c0 + c8) = v;
    }
  }
}

// ---- grouped edge pass: 4 nodes/block, T pre-unpacked, dual acc -----------
__global__ __launch_bounds__(256) void k_group(const unsigned short* __restrict__ Tc,
                                               const unsigned short* __restrict__ s_bf,
                                               const float* __restrict__ xb2,
                                               const int* __restrict__ ei,
                                               const int* __restrict__ eptr,
                                               const int* __restrict__ eord,
                                               float* __restrict__ agg) {
  const int n = blockIdx.x * 4 + (threadIdx.x >> 6);
  const int lane = threadIdx.x & 63;
  const int beg = eptr[n], end = eptr[n + 1];
  if (beg == end) return;
  const uint4* trow = reinterpret_cast<const uint4*>(Tc + (size_t)n * 8192 + (size_t)lane * 128);
  float tf[128];
#pragma unroll
  for (int j = 0; j < 16; j++) {
    uint4 v = trow[j];
    tf[8 * j + 0] = b2f_lo(v.x); tf[8 * j + 1] = b2f_hi(v.x);
    tf[8 * j + 2] = b2f_lo(v.y); tf[8 * j + 3] = b2f_hi(v.y);
    tf[8 * j + 4] = b2f_lo(v.z); tf[8 * j + 5] = b2f_hi(v.z);
    tf[8 * j + 6] = b2f_lo(v.w); tf[8 * j + 7] = b2f_hi(v.w);
  }
  const float xbv = xb2[(size_t)n * 64 + lane];
  for (int j = beg; j < end; j++) {
    int e = eord[j];
    int dst = ei[EE + e];
    int sw = ((const int*)(s_bf + (size_t)e * 128))[lane];
    float a0 = 0.0f, a1 = 0.0f;
#pragma unroll
    for (int q = 0; q < 64; q += 2) {
      unsigned s0 = (unsigned)__builtin_amdgcn_readlane(sw, q);
      unsigned s1 = (unsigned)__builtin_amdgcn_readlane(sw, q + 1);
      a0 += b2f_lo(s0) * tf[2 * q] + b2f_hi(s0) * tf[2 * q + 1];
      a1 += b2f_lo(s1) * tf[2 * q + 2] + b2f_hi(s1) * tf[2 * q + 3];
    }
    atomicAdd(agg + (size_t)dst * 64 + lane, a0 + a1 + xbv);
  }
}

// ---- fallback per-edge chunk dot (KC<128) ---------------------------------
template <int KC>
__global__ __launch_bounds__(256) void k_emsg(const unsigned short* __restrict__ Tc,
                                              const unsigned short* __restrict__ s_bf,
                                              const int* __restrict__ ei,
                                              float* __restrict__ m, int K0, int first) {
  int e = blockIdx.x * 4 + (threadIdx.x >> 6);
  int o = threadIdx.x & 63;
  int src = ei[e];
  const uint4* tv = reinterpret_cast<const uint4*>(Tc + ((size_t)src * 64 + o) * KC);
  const uint4* sv = reinterpret_cast<const uint4*>(s_bf + (size_t)e * 128 + K0);
  float acc = 0.0f;
#pragma unroll
  for (int j = 0; j < KC / 8; j++) {
    uint4 a = tv[j], b = sv[j];
    unsigned aa[4] = {a.x, a.y, a.z, a.w};
    unsigned bb[4] = {b.x, b.y, b.z, b.w};
#pragma unroll
    for (int q = 0; q < 4; q++)
      acc += b2f_lo(aa[q]) * b2f_lo(bb[q]) + b2f_hi(aa[q]) * b2f_hi(bb[q]);
  }
  float* mp = m + (size_t)e * 64 + o;
  if (first) *mp = acc;
  else *mp += acc;
}

__global__ __launch_bounds__(256) void k_aggm(const float* __restrict__ m,
                                              const float* __restrict__ xb2,
                                              const int* __restrict__ ei,
                                              float* __restrict__ agg) {
  int e = blockIdx.x * 4 + (threadIdx.x >> 6);
  int o = threadIdx.x & 63;
  int src = ei[e], dst = ei[EE + e];
  atomicAdd(agg + (size_t)dst * 64 + o, m[(size_t)e * 64 + o] + xb2[(size_t)src * 64 + o]);
}

// ---- fused xc + GRU + next-layer xb2/agg0 ---------------------------------
__global__ __launch_bounds__(256) void k_xcgru(float* __restrict__ x,
                                               unsigned short* __restrict__ xb,
                                               float* __restrict__ agg,
                                               const float* __restrict__ invd,
                                               const float* __restrict__ rW,
                                               const float* __restrict__ rb,
                                               const float* __restrict__ Wih,
                                               const float* __restrict__ Whh,
                                               const float* __restrict__ bih,
                                               const float* __restrict__ bhh,
                                               const float* __restrict__ b2,
                                               float* __restrict__ xb2) {
  __shared__ float Ax[64 * 34];    // old x, then new x, [k][n]
  __shared__ float Axc[64 * 34];   // xc, [k][n]
  __shared__ float Bt[64 * 200];   // weights [k][o]
  const int t = threadIdx.x;
  const int n0 = blockIdx.x * 32;
  const int tn = t >> 4, to = t & 15;

  // stage old x + rootW
  for (int p = t; p < 32 * 64; p += 256) {
    int n = p >> 6, k = p & 63;
    Ax[k * 34 + n] = (n0 + n < NN) ? x[(n0 + n) * 64 + k] : 0.0f;
  }
  for (int p = t; p < 64 * 64; p += 256) {
    int o = p >> 6, k = p & 63;
    Bt[k * 200 + o] = rW[p];
  }
  __syncthreads();

  // xc = silu(x@rW.T + rb + agg*invd); write into Axc; zero agg
  {
    float acc[2][4] = {{0, 0, 0, 0}, {0, 0, 0, 0}};
    for (int k = 0; k < 64; k++) {
      f32x2 a = *reinterpret_cast<const f32x2*>(&Ax[k * 34 + tn * 2]);
      f32x4 b = *reinterpret_cast<const f32x4*>(&Bt[k * 200 + to * 4]);
#pragma unroll
      for (int j = 0; j < 4; j++) {
        acc[0][j] += a[0] * b[j];
        acc[1][j] += a[1] * b[j];
      }
    }
#pragma unroll
    for (int nn = 0; nn < 2; nn++) {
      int n = n0 + tn * 2 + nn;
#pragma unroll
      for (int j = 0; j < 4; j++) {
        int o = to * 4 + j;
        float v = 0.0f;
        if (n < NN) {
          v = siluf(acc[nn][j] + rb[o] + agg[(size_t)n * 64 + o] * invd[n]);
          agg[(size_t)n * 64 + o] = 0.0f;
        }
        Axc[o * 34 + tn * 2 + nn] = v;
      }
    }
  }
  __syncthreads();
  // load Wih
  for (int p = t; p < 192 * 64; p += 256) {
    int o = p >> 6, k = p & 63;
    Bt[k * 200 + o] = Wih[p];
  }
  __syncthreads();
  float ai[2][3][4], ah[2][3][4];
#pragma unroll
  for (int j = 0; j < 3; j++)
#pragma unroll
    for (int hh = 0; hh < 4; hh++) {
      float bv = bih[j * 64 + to * 4 + hh];
      ai[0][j][hh] = bv; ai[1][j][hh] = bv;
      float bv2 = bhh[j * 64 + to * 4 + hh];
      ah[0][j][hh] = bv2; ah[1][j][hh] = bv2;
    }
  for (int k = 0; k < 64; k++) {
    f32x2 a = *reinterpret_cast<const f32x2*>(&Axc[k * 34 + tn * 2]);
#pragma unroll
    for (int j = 0; j < 3; j++) {
      f32x4 b = *reinterpret_cast<const f32x4*>(&Bt[k * 200 + j * 64 + to * 4]);
#pragma unroll
      for (int hh = 0; hh < 4; hh++) {
        ai[0][j][hh] += a[0] * b[hh];
        ai[1][j][hh] += a[1] * b[hh];
      }
    }
  }
  __syncthreads();
  for (int p = t; p < 192 * 64; p += 256) {
    int o = p >> 6, k = p & 63;
    Bt[k * 200 + o] = Whh[p];
  }
  __syncthreads();
  for (int k = 0; k < 64; k++) {
    f32x2 a = *reinterpret_cast<const f32x2*>(&Ax[k * 34 + tn * 2]);
#pragma unroll
    for (int j = 0; j < 3; j++) {
      f32x4 b = *reinterpret_cast<const f32x4*>(&Bt[k * 200 + j * 64 + to * 4]);
#pragma unroll
      for (int hh = 0; hh < 4; hh++) {
        ah[0][j][hh] += a[0] * b[hh];
        ah[1][j][hh] += a[1] * b[hh];
      }
    }
  }
  __syncthreads();  // Ax & Bt reads done

  // gates; write new x/xb; update Ax (own slots) to new x; load Bt=b2
#pragma unroll
  for (int nn = 0; nn < 2; nn++) {
    int n = n0 + tn * 2 + nn;
    f32x4 xn;
#pragma unroll
    for (int hh = 0; hh < 4; hh++) {
      float r = sigm(ai[nn][0][hh] + ah[nn][0][hh]);
      float z = sigm(ai[nn][1][hh] + ah[nn][1][hh]);
      float ng = tanhf(ai[nn][2][hh] + r * ah[nn][2][hh]);
      float hold = Ax[(to * 4 + hh) * 34 + tn * 2 + nn];
      xn[hh] = (1.0f - z) * ng + z * hold;
      Ax[(to * 4 + hh) * 34 + tn * 2 + nn] = xn[hh];
    }
    if (n < NN) {
      *reinterpret_cast<f32x4*>(x + n * 64 + to * 4) = xn;
      unsigned p0 = (unsigned)f2b(xn[0]) | ((unsigned)f2b(xn[1]) << 16);
      unsigned p1 = (unsigned)f2b(xn[2]) | ((unsigned)f2b(xn[3]) << 16);
      *reinterpret_cast<uint2*>(xb + (size_t)n * 64 + to * 4) = make_uint2(p0, p1);
    }
  }
  for (int p = t; p < 64 * 64; p += 256) {
    int i = p >> 6, o = p & 63;
    Bt[i * 200 + o] = b2[p];
  }
  __syncthreads();

  // xb2 = x_new @ b2 (b2 indexed [i*64+o])
  {
    float acc[2][4] = {{0, 0, 0, 0}, {0, 0, 0, 0}};
    for (int i = 0; i < 64; i++) {
      f32x2 a = *reinterpret_cast<const f32x2*>(&Ax[i * 34 + tn * 2]);
      f32x4 b = *reinterpret_cast<const f32x4*>(&Bt[i * 200 + to * 4]);
#pragma unroll
      for (int j = 0; j < 4; j++) {
        acc[0][j] += a[0] * b[j];
        acc[1][j] += a[1] * b[j];
      }
    }
#pragma unroll
    for (int nn = 0; nn < 2; nn++) {
      int n = n0 + tn * 2 + nn;
      if (n < NN)
        *reinterpret_cast<f32x4*>(xb2 + (size_t)n * 64 + to * 4) =
            *reinterpret_cast<f32x4*>(&acc[nn][0]);
    }
  }
}

// ---- fused Set2Set (batch is sorted -> contiguous graphs) + out head ------
__global__ __launch_bounds__(64) void k_s2s(const float* __restrict__ x,
                                            const int* __restrict__ batch,
                                            const float* __restrict__ Wih,
                                            const float* __restrict__ Whh,
                                            const float* __restrict__ bih,
                                            const float* __restrict__ bhh,
                                            const float* __restrict__ W1,
                                            const float* __restrict__ b1,
                                            const float* __restrict__ W2,
                                            const float* __restrict__ b2o,
                                            void* __restrict__ out,
                                            const int* __restrict__ flag) {
  const int b = blockIdx.x, lane = threadIdx.x;
  int lo = 0, hi = NN;
  while (lo < hi) { int mid = (lo + hi) >> 1; if (batch[mid] < b) lo = mid + 1; else hi = mid; }
  const int ns = lo;
  hi = NN;
  while (lo < hi) { int mid = (lo + hi) >> 1; if (batch[mid] <= b) lo = mid + 1; else hi = mid; }
  const int ne = lo;
  const int cnt = ne - ns;

  __shared__ float hs[64], rs[64], es[512];
  hs[lane] = 0.0f;
  rs[lane] = 0.0f;
  float cl = 0.0f;
  __syncthreads();

  for (int step = 0; step < 3; step++) {
    float g[4];
#pragma unroll
    for (int j = 0; j < 4; j++) {
      int row = j * 64 + lane;
      float acc = bih[row] + bhh[row];
      for (int k = 0; k < 64; k++)
        acc += hs[k] * (Wih[row * 128 + k] + Whh[row * 64 + k]);
      for (int k = 0; k < 64; k++)
        acc += rs[k] * Wih[row * 128 + 64 + k];
      g[j] = acc;
    }
    float ig = sigm(g[0]), fg = sigm(g[1]), gg = tanhf(g[2]), og = sigm(g[3]);
    cl = fg * cl + ig * gg;
    float h = og * tanhf(cl);
    __syncthreads();
    hs[lane] = h;
    __syncthreads();

    if (cnt > 0) {
      float mx = -3.4e38f;
      for (int base = 0; base < cnt; base += 64) {
        int idx = base + lane;
        float e = -3.4e38f;
        if (idx < cnt) {
          int node = ns + idx;
          float s = 0.0f;
          for (int k = 0; k < 64; k++) s += x[(size_t)node * 64 + k] * hs[k];
          if (idx < 512) es[idx] = s;
          e = s;
        }
#pragma unroll
        for (int mm = 32; mm; mm >>= 1) e = fmaxf(e, __shfl_xor(e, mm, 64));
        mx = fmaxf(mx, e);
      }
      float tot = 0.0f;
      for (int base = 0; base < cnt; base += 64) {
        int idx = base + lane;
        float a = 0.0f;
        if (idx < cnt && idx < 512) { a = __expf(es[idx] - mx); es[idx] = a; }
#pragma unroll
        for (int mm = 32; mm; mm >>= 1) a += __shfl_xor(a, mm, 64);
        tot += a;
      }
      __syncthreads();
      float inv = 1.0f / tot;
      float r = 0.0f;
      int cc = cnt < 512 ? cnt : 512;
      for (int j = 0; j < cc; j++) r += es[j] * x[(size_t)(ns + j) * 64 + lane];
      r *= inv;
      __syncthreads();
      rs[lane] = r;
    } else {
      rs[lane] = 0.0f;
    }
    __syncthreads();
  }

  // out head
  float acc = b1[lane];
  for (int k = 0; k < 64; k++) acc += hs[k] * W1[lane * 128 + k];
  for (int k = 0; k < 64; k++) acc += rs[k] * W1[lane * 128 + 64 + k];
  float u = siluf(acc) * W2[lane];
#pragma unroll
  for (int mm = 32; mm; mm >>= 1) u += __shfl_xor(u, mm, 64);
  if (lane == 0) {
    float v = u + b2o[0];
    if (*flag) ((unsigned short*)out)[b] = f2b(v);
    else ((float*)out)[b] = v;
  }
}

// ---------------------------------------------------------------------------
template <int KC>
static void run_chunks(const unsigned short* xb, const unsigned short* W2t,
                       unsigned short* Tc, const unsigned short* s_bf,
                       const int* ei, float* m, hipStream_t stream) {
  const int nch = 128 / KC;
  for (int c = 0; c < nch; c++) {
    k_T<KC><<<dim3((NN + 127) / 128, (64 * KC) / 128), 256, 0, stream>>>(xb, W2t, Tc, c * KC);
    k_emsg<KC><<<EE / 4, 256, 0, stream>>>(Tc, s_bf, ei, m, c * KC, c == 0 ? 1 : 0);
  }
}

extern "C" void kernel_launch(void* const* d_in, const int* in_sizes, int n_in,
                              void* d_out, int out_size, void* d_ws, size_t ws_size,
                              hipStream_t stream) {
  (void)n_in; (void)out_size;
  const bool sig_order = (in_sizes[1] == 2 * EE);
  const void* p_x   = d_in[0];
  const void* p_ea  = sig_order ? d_in[2] : d_in[1];
  const void* p_pos = sig_order ? d_in[3] : d_in[2];
  const int* edge_index = (const int*)(sig_order ? d_in[1] : d_in[3]);
  const int* batch      = (const int*)d_in[4];
  const void* p_w[20];
  for (int i = 0; i < 20; i++) p_w[i] = d_in[5 + i];

  char* base = (char*)d_ws;
  size_t off = 0;
  auto alloc = [&](size_t bytes) -> char* {
    char* p = base + off;
    off = (off + bytes + 255) & ~(size_t)255;
    return p;
  };
  int* flag = (int*)alloc(4);
  static const int cvt_n[NCVT] = {
      64 * 11, 64, 128 * 5, 128, 4096 * 128, 4096,
      64 * 64, 64,
      192 * 64, 192 * 64, 192, 192,
      256 * 128, 256 * 64, 256, 256,
      64 * 128, 64, 64, 1};
  float* canon[NCVT];
  for (int i = 0; i < NCVT; i++) canon[i] = (float*)alloc((size_t)cvt_n[i] * 4);
  const float* c_flW  = canon[0];
  const float* c_flb  = canon[1];
  const float* c_W1   = canon[2];
  const float* c_b1   = canon[3];
  const float* c_W2   = canon[4];
  const float* c_b2   = canon[5];
  const float* c_rW   = canon[6];
  const float* c_rb   = canon[7];
  const float* c_gWih = canon[8];
  const float* c_gWhh = canon[9];
  const float* c_gbih = canon[10];
  const float* c_gbhh = canon[11];
  const float* c_lWih = canon[12];
  const float* c_lWhh = canon[13];
  const float* c_lbih = canon[14];
  const float* c_lbhh = canon[15];
  const float* c_oW1  = canon[16];
  const float* c_ob1  = canon[17];
  const float* c_oW2  = canon[18];
  const float* c_ob2  = canon[19];

  unsigned short* s_bf = (unsigned short*)alloc((size_t)EE * 128 * 2);
  float* m    = (float*)alloc((size_t)EE * 64 * 4);  // fallback only
  float* x    = (float*)alloc((size_t)NN * 64 * 4);
  unsigned short* xb = (unsigned short*)alloc((size_t)NN * 64 * 2);
  float* agg  = (float*)alloc((size_t)NN * 64 * 4);
  float* xb2  = (float*)alloc((size_t)NN * 64 * 4);
  unsigned short* W2t = (unsigned short*)alloc((size_t)4096 * 128 * 2);
  float* invd = (float*)alloc((size_t)NN * 4);
  int* cnt    = (int*)alloc((size_t)2 * NN * 4);
  int* cntd   = cnt + NN;
  int* eptr   = (int*)alloc((size_t)(NN + 1) * 4);
  int* cursor = (int*)alloc((size_t)NN * 4);
  int* eord   = (int*)alloc((size_t)EE * 4);
  size_t base_need = off;

  int KC = 0;
  const int kcs[5] = {128, 64, 32, 16, 8};
  for (int i = 0; i < 5; i++) {
    size_t need = base_need + (size_t)NN * 64 * kcs[i] * 2 + 256;
    if (need <= ws_size) { KC = kcs[i]; break; }
  }
  if (KC == 0) return;
  unsigned short* Tc = (unsigned short*)alloc((size_t)NN * 64 * KC * 2);

  // ---- dtype detect + weight convert ----
  k_detect<<<1, 256, 0, stream>>>((const unsigned*)p_ea, flag);
  Cvt cvt;
  for (int i = 0; i < 20; i++) cvt.src[i] = p_w[i];
  for (int i = 0; i < NCVT; i++) { cvt.dst[i] = canon[i]; cvt.n[i] = cvt_n[i]; }
  k_convert<<<512, 256, 0, stream>>>(cvt, flag);

  // ---- prologue ----
  hipMemsetAsync(cnt, 0, (size_t)2 * NN * 4, stream);
  k_lift<<<NN / 4, 256, 0, stream>>>(p_x, c_flW, c_flb, c_b2, x, xb, xb2, agg, flag);
  k_sdeg<<<EE / 2, 256, 0, stream>>>(p_ea, p_pos, edge_index, c_W1, c_b1, s_bf, flag);
  k_w2t<<<(4096 * 128) / 256, 256, 0, stream>>>(c_W2, W2t);
  k_hist<<<(EE + 255) / 256, 256, 0, stream>>>(edge_index, cnt, cntd);
  k_scan<<<1, 256, 0, stream>>>(cnt, cntd, eptr, cursor, invd);
  k_scatter<<<(EE + 255) / 256, 256, 0, stream>>>(edge_index, cursor, eord);

  // ---- 4 message-passing layers ----
  for (int layer = 0; layer < 4; layer++) {
    if (KC == 128) {
      k_T<128><<<dim3((NN + 127) / 128, 64), 256, 0, stream>>>(xb, W2t, Tc, 0);
      k_group<<<NN / 4, 256, 0, stream>>>(Tc, s_bf, xb2, edge_index, eptr, eord, agg);
    } else {
      switch (KC) {
        case 64: run_chunks<64>(xb, W2t, Tc, s_bf, edge_index, m, stream); break;
        case 32: run_chunks<32>(xb, W2t, Tc, s_bf, edge_index, m, stream); break;
        case 16: run_chunks<16>(xb, W2t, Tc, s_bf, edge_index, m, stream); break;
        default: run_chunks<8>(xb, W2t, Tc, s_bf, edge_index, m, stream); break;
      }
      k_aggm<<<EE / 4, 256, 0, stream>>>(m, xb2, edge_index, agg);
    }
    k_xcgru<<<(NN + 31) / 32, 256, 0, stream>>>(x, xb, agg, invd, c_rW, c_rb,
                                                c_gWih, c_gWhh, c_gbih, c_gbhh,
                                                c_b2, xb2);
  }

  // ---- Set2Set + output head (one kernel; batch is sorted) ----
  k_s2s<<<BBG, 64, 0, stream>>>(x, batch, c_lWih, c_lWhh, c_lbih, c_lbhh,
                                c_oW1, c_ob1, c_oW2, c_ob2, d_out, flag);
}

// Round 7
// 1016.474 us; speedup vs baseline: 1.0008x; 1.0008x over previous
//
#include <hip/hip_runtime.h>
#include <stdint.h>

// ---------------------------------------------------------------------------
// SpatialGNN forward, round 7.
// R6: 1017us (regression). k_s2s was latency-bound: 64-thr/graph (2 waves/CU)
// + uncoalesced LSTM weight reads (stride-512B across lanes). R7 fixes ONLY
// k_s2s: 256 thr/block (4 waves/graph), transposed LSTM/head weights
// (coalesced 256B/wave loads), wave-parallel e/softmax/r with LDS reductions.
// Everything else unchanged from R6.
// ---------------------------------------------------------------------------

#define NN 10000
#define EE 50000
#define BBG 512

typedef __attribute__((ext_vector_type(8))) short short8;
typedef __attribute__((ext_vector_type(4))) float f32x4;
typedef __attribute__((ext_vector_type(2))) float f32x2;

__device__ __forceinline__ float b2f(unsigned short u) {
  return __uint_as_float(((unsigned)u) << 16);
}
__device__ __forceinline__ float b2f_lo(unsigned u) { return __uint_as_float(u << 16); }
__device__ __forceinline__ float b2f_hi(unsigned u) { return __uint_as_float(u & 0xFFFF0000u); }
__device__ __forceinline__ unsigned short f2b(float f) {
  unsigned u = __float_as_uint(f);
  u += 0x7FFFu + ((u >> 16) & 1u);  // RNE
  return (unsigned short)(u >> 16);
}
__device__ __forceinline__ float sigm(float x) { return 1.0f / (1.0f + __expf(-x)); }
__device__ __forceinline__ float siluf(float x) { return x / (1.0f + __expf(-x)); }
__device__ __forceinline__ float rawf(const void* p, int f, int i) {
  return f ? b2f(((const unsigned short*)p)[i]) : ((const float*)p)[i];
}

// ---------------- dtype detection on edge_attr (uniform[0,1)) --------------
__global__ __launch_bounds__(256) void k_detect(const unsigned* __restrict__ w,
                                                int* __restrict__ flag) {
  __shared__ int cnt;
  if (threadIdx.x == 0) cnt = 0;
  __syncthreads();
  int c = 0;
  for (int i = threadIdx.x; i < 4096; i += 256) {
    unsigned lo = w[i] & 0xFFFFu;
    if (lo - 0x3A00u < 0x600u) c++;
  }
  atomicAdd(&cnt, c);
  __syncthreads();
  if (threadIdx.x == 0) *flag = (cnt > 2048) ? 1 : 0;  // 1 = inputs are bf16
}

// ---------------- convert weight inputs to canonical fp32 ------------------
#define NCVT 20
struct Cvt {
  const void* src[NCVT];
  float* dst[NCVT];
  int n[NCVT];
};

__global__ __launch_bounds__(256) void k_convert(Cvt c, const int* __restrict__ flag) {
  const int f = *flag;
  const int stride = gridDim.x * blockDim.x;
  const int tid = blockIdx.x * blockDim.x + threadIdx.x;
#pragma unroll 1
  for (int a = 0; a < NCVT; a++) {
    const int n = c.n[a];
    const float* sf = (const float*)c.src[a];
    const unsigned short* sb = (const unsigned short*)c.src[a];
    float* d = c.dst[a];
    for (int i = tid; i < n; i += stride) d[i] = f ? b2f(sb[i]) : sf[i];
  }
}

// ---- LSTM/head weight transposes for coalesced k_s2s access ---------------
__global__ __launch_bounds__(256) void k_ltrans(const float* __restrict__ Wih,
                                                const float* __restrict__ Whh,
                                                const float* __restrict__ W1,
                                                float* __restrict__ WihT,
                                                float* __restrict__ WhhT,
                                                float* __restrict__ W1T) {
  int j = blockIdx.x * 256 + threadIdx.x;
  if (j < 32768) {
    int r = j & 255, k = j >> 8;
    WihT[k * 256 + r] = Wih[r * 128 + k];
  } else if (j < 49152) {
    int q = j - 32768;
    int r = q & 255, k = q >> 8;
    WhhT[k * 256 + r] = Whh[r * 64 + k];
  } else if (j < 57344) {
    int q = j - 49152;
    int o = q & 63, k = q >> 6;
    W1T[k * 64 + o] = W1[o * 128 + k];
  }
}

// ---------------- CSR by src + dst degree histogram ------------------------
__global__ __launch_bounds__(256) void k_hist(const int* __restrict__ ei,
                                              int* __restrict__ cnt,
                                              int* __restrict__ cntd) {
  int e = blockIdx.x * 256 + threadIdx.x;
  if (e < EE) {
    atomicAdd(cnt + ei[e], 1);
    atomicAdd(cntd + ei[EE + e], 1);
  }
}

__global__ __launch_bounds__(256) void k_scan(const int* __restrict__ cnt,
                                              const int* __restrict__ cntd,
                                              int* __restrict__ eptr,
                                              int* __restrict__ cursor,
                                              float* __restrict__ invd) {
  __shared__ int part[256];
  const int t = threadIdx.x;
  const int c0 = t * 40;
  int s = 0;
  for (int i = 0; i < 40; i++) {
    int idx = c0 + i;
    if (idx < NN) s += cnt[idx];
  }
  part[t] = s;
  __syncthreads();
  if (t == 0) {
    int run = 0;
    for (int i = 0; i < 256; i++) { int v = part[i]; part[i] = run; run += v; }
  }
  __syncthreads();
  int run = part[t];
  for (int i = 0; i < 40; i++) {
    int idx = c0 + i;
    if (idx < NN) {
      eptr[idx] = run;
      cursor[idx] = run;
      run += cnt[idx];
      invd[idx] = 1.0f / fmaxf((float)cntd[idx], 1.0f);
    }
  }
  if (t == 255) eptr[NN] = EE;
}

__global__ __launch_bounds__(256) void k_scatter(const int* __restrict__ ei,
                                                 int* __restrict__ cursor,
                                                 int* __restrict__ eord) {
  int e = blockIdx.x * 256 + threadIdx.x;
  if (e < EE) {
    int pos = atomicAdd(cursor + ei[e], 1);
    eord[pos] = e;
  }
}

// -------- lift: x = silu(x_in@flW.T+flb); also xb, xb2, agg=0 --------------
__global__ __launch_bounds__(256) void k_lift(const void* __restrict__ xin,
                                              const float* __restrict__ flW,
                                              const float* __restrict__ flb,
                                              const float* __restrict__ b2,
                                              float* __restrict__ x,
                                              unsigned short* __restrict__ xb,
                                              float* __restrict__ xb2,
                                              float* __restrict__ agg,
                                              const int* __restrict__ flag) {
  const int f = *flag;
  int node = blockIdx.x * 4 + (threadIdx.x >> 6);
  int h = threadIdx.x & 63;
  float acc = flb[h];
#pragma unroll
  for (int c = 0; c < 11; c++)
    acc += rawf(xin, f, node * 11 + c) * flW[h * 11 + c];
  float v = siluf(acc);
  x[node * 64 + h] = v;
  xb[node * 64 + h] = f2b(v);
  int xvi = __float_as_int(v);
  float a2 = 0.0f;
#pragma unroll 8
  for (int i = 0; i < 64; i++) {
    float xi = __int_as_float(__builtin_amdgcn_readlane(xvi, i));
    a2 += xi * b2[i * 64 + h];
  }
  xb2[node * 64 + h] = a2;
  agg[(size_t)node * 64 + h] = 0.0f;
}

// ---------- s[e,k] = silu(ef @ nn_W1.T + nn_b1) bf16 -----------------------
__global__ __launch_bounds__(256) void k_sdeg(const void* __restrict__ ea,
                                              const void* __restrict__ pos,
                                              const int* __restrict__ ei,
                                              const float* __restrict__ W1,
                                              const float* __restrict__ b1,
                                              unsigned short* __restrict__ s_bf,
                                              const int* __restrict__ flag) {
  const int f = *flag;
  int e = blockIdx.x * 2 + (threadIdx.x >> 7);
  int k = threadIdx.x & 127;
  int src = ei[e], dst = ei[EE + e];
  float dx = rawf(pos, f, src * 3 + 0) - rawf(pos, f, dst * 3 + 0);
  float dy = rawf(pos, f, src * 3 + 1) - rawf(pos, f, dst * 3 + 1);
  float dz = rawf(pos, f, src * 3 + 2) - rawf(pos, f, dst * 3 + 2);
  float dist = sqrtf(dx * dx + dy * dy + dz * dz);
  float acc = b1[k];
  acc += rawf(ea, f, e * 4 + 0) * W1[k * 5 + 0];
  acc += rawf(ea, f, e * 4 + 1) * W1[k * 5 + 1];
  acc += rawf(ea, f, e * 4 + 2) * W1[k * 5 + 2];
  acc += rawf(ea, f, e * 4 + 3) * W1[k * 5 + 3];
  acc += dist * W1[k * 5 + 4];
  s_bf[e * 128 + k] = f2b(siluf(acc));
}

// ---- W2t[(o*128+k)*64 + i] = bf16(W2[(i*64+o)*128 + k]) -------------------
__global__ __launch_bounds__(256) void k_w2t(const float* __restrict__ W2,
                                             unsigned short* __restrict__ W2t) {
  int j = blockIdx.x * 256 + threadIdx.x;
  int i = j & 63;
  int k = (j >> 6) & 127;
  int o = j >> 13;
  W2t[j] = f2b(W2[(size_t)(i * 64 + o) * 128 + k]);
}

// ---- T GEMM with LDS-staged coalesced epilogue ----------------------------
template <int KC>
__global__ __launch_bounds__(256) void k_T(const unsigned short* __restrict__ xb,
                                           const unsigned short* __restrict__ W2t,
                                           unsigned short* __restrict__ Tc, int K0) {
  __shared__ unsigned short sh[2 * 128 * 72];
  unsigned short* As = sh;
  unsigned short* Bs = sh + 128 * 72;
  const int t = threadIdx.x;
  const int n0 = blockIdx.x * 128;
  const int c0 = blockIdx.y * 128;
  const int lane = t & 63;
  const int w = t >> 6;
  const int lm = lane & 15;
  const int quad = lane >> 4;
  const int wm = w & 1;
  const int wn = w >> 1;

  for (int p = t; p < 128 * 8; p += 256) {
    int r = p >> 3, cc = (p & 7) * 8;
    uint4 v = make_uint4(0u, 0u, 0u, 0u);
    if (n0 + r < NN) v = *reinterpret_cast<const uint4*>(xb + (size_t)(n0 + r) * 64 + cc);
    *reinterpret_cast<uint4*>(&As[r * 72 + cc]) = v;
  }
  for (int p = t; p < 128 * 8; p += 256) {
    int r = p >> 3, cc = (p & 7) * 8;
    int c = c0 + r;
    int o = c / KC;
    int kg = K0 + (c % KC);
    uint4 v = *reinterpret_cast<const uint4*>(W2t + (size_t)(o * 128 + kg) * 64 + cc);
    *reinterpret_cast<uint4*>(&Bs[r * 72 + cc]) = v;
  }
  __syncthreads();

  f32x4 acc[4][4];
#pragma unroll
  for (int mt = 0; mt < 4; mt++)
#pragma unroll
    for (int nt = 0; nt < 4; nt++) acc[mt][nt] = (f32x4)(0.0f);

#pragma unroll
  for (int ks = 0; ks < 2; ks++) {
    const int kk = ks * 32 + quad * 8;
    short8 af[4], bfr[4];
#pragma unroll
    for (int mt = 0; mt < 4; mt++)
      af[mt] = *reinterpret_cast<const short8*>(&As[(wm * 64 + mt * 16 + lm) * 72 + kk]);
#pragma unroll
    for (int nt = 0; nt < 4; nt++)
      bfr[nt] = *reinterpret_cast<const short8*>(&Bs[(wn * 64 + nt * 16 + lm) * 72 + kk]);
#pragma unroll
    for (int mt = 0; mt < 4; mt++)
#pragma unroll
      for (int nt = 0; nt < 4; nt++)
        acc[mt][nt] = __builtin_amdgcn_mfma_f32_16x16x32_bf16(af[mt], bfr[nt], acc[mt][nt], 0, 0, 0);
  }

  __syncthreads();
  unsigned short* st = sh;
#pragma unroll
  for (int nt = 0; nt < 4; nt++) {
    int col = wn * 64 + nt * 16 + lm;
#pragma unroll
    for (int mt = 0; mt < 4; mt++) {
#pragma unroll
      for (int reg = 0; reg < 4; reg++) {
        int row = wm * 64 + mt * 16 + quad * 4 + reg;
        st[row * 132 + col] = f2b(acc[mt][nt][reg]);
      }
    }
  }
  __syncthreads();
  const int r16 = t >> 4;
  const int c8 = (t & 15) * 8;
#pragma unroll
  for (int it = 0; it < 8; it++) {
    int row = it * 16 + r16;
    int n = n0 + row;
    if (n < NN) {
      uint2 v0 = *reinterpret_cast<const uint2*>(&st[row * 132 + c8]);
      uint2 v1 = *reinterpret_cast<const uint2*>(&st[row * 132 + c8 + 4]);
      uint4 v = make_uint4(v0.x, v0.y, v1.x, v1.y);
      *reinterpret_cast<uint4*>(Tc + (size_t)n * (64 * KC) + c0 + c8) = v;
    }
  }
}

// ---- grouped edge pass: 4 nodes/block, T pre-unpacked, dual acc -----------
__global__ __launch_bounds__(256) void k_group(const unsigned short* __restrict__ Tc,
                                               const unsigned short* __restrict__ s_bf,
                                               const float* __restrict__ xb2,
                                               const int* __restrict__ ei,
                                               const int* __restrict__ eptr,
                                               const int* __restrict__ eord,
                                               float* __restrict__ agg) {
  const int n = blockIdx.x * 4 + (threadIdx.x >> 6);
  const int lane = threadIdx.x & 63;
  const int beg = eptr[n], end = eptr[n + 1];
  if (beg == end) return;
  const uint4* trow = reinterpret_cast<const uint4*>(Tc + (size_t)n * 8192 + (size_t)lane * 128);
  float tf[128];
#pragma unroll
  for (int j = 0; j < 16; j++) {
    uint4 v = trow[j];
    tf[8 * j + 0] = b2f_lo(v.x); tf[8 * j + 1] = b2f_hi(v.x);
    tf[8 * j + 2] = b2f_lo(v.y); tf[8 * j + 3] = b2f_hi(v.y);
    tf[8 * j + 4] = b2f_lo(v.z); tf[8 * j + 5] = b2f_hi(v.z);
    tf[8 * j + 6] = b2f_lo(v.w); tf[8 * j + 7] = b2f_hi(v.w);
  }
  const float xbv = xb2[(size_t)n * 64 + lane];
  for (int j = beg; j < end; j++) {
    int e = eord[j];
    int dst = ei[EE + e];
    int sw = ((const int*)(s_bf + (size_t)e * 128))[lane];
    float a0 = 0.0f, a1 = 0.0f;
#pragma unroll
    for (int q = 0; q < 64; q += 2) {
      unsigned s0 = (unsigned)__builtin_amdgcn_readlane(sw, q);
      unsigned s1 = (unsigned)__builtin_amdgcn_readlane(sw, q + 1);
      a0 += b2f_lo(s0) * tf[2 * q] + b2f_hi(s0) * tf[2 * q + 1];
      a1 += b2f_lo(s1) * tf[2 * q + 2] + b2f_hi(s1) * tf[2 * q + 3];
    }
    atomicAdd(agg + (size_t)dst * 64 + lane, a0 + a1 + xbv);
  }
}

// ---- fallback per-edge chunk dot (KC<128) ---------------------------------
template <int KC>
__global__ __launch_bounds__(256) void k_emsg(const unsigned short* __restrict__ Tc,
                                              const unsigned short* __restrict__ s_bf,
                                              const int* __restrict__ ei,
                                              float* __restrict__ m, int K0, int first) {
  int e = blockIdx.x * 4 + (threadIdx.x >> 6);
  int o = threadIdx.x & 63;
  int src = ei[e];
  const uint4* tv = reinterpret_cast<const uint4*>(Tc + ((size_t)src * 64 + o) * KC);
  const uint4* sv = reinterpret_cast<const uint4*>(s_bf + (size_t)e * 128 + K0);
  float acc = 0.0f;
#pragma unroll
  for (int j = 0; j < KC / 8; j++) {
    uint4 a = tv[j], b = sv[j];
    unsigned aa[4] = {a.x, a.y, a.z, a.w};
    unsigned bb[4] = {b.x, b.y, b.z, b.w};
#pragma unroll
    for (int q = 0; q < 4; q++)
      acc += b2f_lo(aa[q]) * b2f_lo(bb[q]) + b2f_hi(aa[q]) * b2f_hi(bb[q]);
  }
  float* mp = m + (size_t)e * 64 + o;
  if (first) *mp = acc;
  else *mp += acc;
}

__global__ __launch_bounds__(256) void k_aggm(const float* __restrict__ m,
                                              const float* __restrict__ xb2,
                                              const int* __restrict__ ei,
                                              float* __restrict__ agg) {
  int e = blockIdx.x * 4 + (threadIdx.x >> 6);
  int o = threadIdx.x & 63;
  int src = ei[e], dst = ei[EE + e];
  atomicAdd(agg + (size_t)dst * 64 + o, m[(size_t)e * 64 + o] + xb2[(size_t)src * 64 + o]);
}

// ---- fused xc + GRU + next-layer xb2/agg0 ---------------------------------
__global__ __launch_bounds__(256) void k_xcgru(float* __restrict__ x,
                                               unsigned short* __restrict__ xb,
                                               float* __restrict__ agg,
                                               const float* __restrict__ invd,
                                               const float* __restrict__ rW,
                                               const float* __restrict__ rb,
                                               const float* __restrict__ Wih,
                                               const float* __restrict__ Whh,
                                               const float* __restrict__ bih,
                                               const float* __restrict__ bhh,
                                               const float* __restrict__ b2,
                                               float* __restrict__ xb2) {
  __shared__ float Ax[64 * 34];
  __shared__ float Axc[64 * 34];
  __shared__ float Bt[64 * 200];
  const int t = threadIdx.x;
  const int n0 = blockIdx.x * 32;
  const int tn = t >> 4, to = t & 15;

  for (int p = t; p < 32 * 64; p += 256) {
    int n = p >> 6, k = p & 63;
    Ax[k * 34 + n] = (n0 + n < NN) ? x[(n0 + n) * 64 + k] : 0.0f;
  }
  for (int p = t; p < 64 * 64; p += 256) {
    int o = p >> 6, k = p & 63;
    Bt[k * 200 + o] = rW[p];
  }
  __syncthreads();

  {
    float acc[2][4] = {{0, 0, 0, 0}, {0, 0, 0, 0}};
    for (int k = 0; k < 64; k++) {
      f32x2 a = *reinterpret_cast<const f32x2*>(&Ax[k * 34 + tn * 2]);
      f32x4 b = *reinterpret_cast<const f32x4*>(&Bt[k * 200 + to * 4]);
#pragma unroll
      for (int j = 0; j < 4; j++) {
        acc[0][j] += a[0] * b[j];
        acc[1][j] += a[1] * b[j];
      }
    }
#pragma unroll
    for (int nn = 0; nn < 2; nn++) {
      int n = n0 + tn * 2 + nn;
#pragma unroll
      for (int j = 0; j < 4; j++) {
        int o = to * 4 + j;
        float v = 0.0f;
        if (n < NN) {
          v = siluf(acc[nn][j] + rb[o] + agg[(size_t)n * 64 + o] * invd[n]);
          agg[(size_t)n * 64 + o] = 0.0f;
        }
        Axc[o * 34 + tn * 2 + nn] = v;
      }
    }
  }
  __syncthreads();
  for (int p = t; p < 192 * 64; p += 256) {
    int o = p >> 6, k = p & 63;
    Bt[k * 200 + o] = Wih[p];
  }
  __syncthreads();
  float ai[2][3][4], ah[2][3][4];
#pragma unroll
  for (int j = 0; j < 3; j++)
#pragma unroll
    for (int hh = 0; hh < 4; hh++) {
      float bv = bih[j * 64 + to * 4 + hh];
      ai[0][j][hh] = bv; ai[1][j][hh] = bv;
      float bv2 = bhh[j * 64 + to * 4 + hh];
      ah[0][j][hh] = bv2; ah[1][j][hh] = bv2;
    }
  for (int k = 0; k < 64; k++) {
    f32x2 a = *reinterpret_cast<const f32x2*>(&Axc[k * 34 + tn * 2]);
#pragma unroll
    for (int j = 0; j < 3; j++) {
      f32x4 b = *reinterpret_cast<const f32x4*>(&Bt[k * 200 + j * 64 + to * 4]);
#pragma unroll
      for (int hh = 0; hh < 4; hh++) {
        ai[0][j][hh] += a[0] * b[hh];
        ai[1][j][hh] += a[1] * b[hh];
      }
    }
  }
  __syncthreads();
  for (int p = t; p < 192 * 64; p += 256) {
    int o = p >> 6, k = p & 63;
    Bt[k * 200 + o] = Whh[p];
  }
  __syncthreads();
  for (int k = 0; k < 64; k++) {
    f32x2 a = *reinterpret_cast<const f32x2*>(&Ax[k * 34 + tn * 2]);
#pragma unroll
    for (int j = 0; j < 3; j++) {
      f32x4 b = *reinterpret_cast<const f32x4*>(&Bt[k * 200 + j * 64 + to * 4]);
#pragma unroll
      for (int hh = 0; hh < 4; hh++) {
        ah[0][j][hh] += a[0] * b[hh];
        ah[1][j][hh] += a[1] * b[hh];
      }
    }
  }
  __syncthreads();

#pragma unroll
  for (int nn = 0; nn < 2; nn++) {
    int n = n0 + tn * 2 + nn;
    f32x4 xn;
#pragma unroll
    for (int hh = 0; hh < 4; hh++) {
      float r = sigm(ai[nn][0][hh] + ah[nn][0][hh]);
      float z = sigm(ai[nn][1][hh] + ah[nn][1][hh]);
      float ng = tanhf(ai[nn][2][hh] + r * ah[nn][2][hh]);
      float hold = Ax[(to * 4 + hh) * 34 + tn * 2 + nn];
      xn[hh] = (1.0f - z) * ng + z * hold;
      Ax[(to * 4 + hh) * 34 + tn * 2 + nn] = xn[hh];
    }
    if (n < NN) {
      *reinterpret_cast<f32x4*>(x + n * 64 + to * 4) = xn;
      unsigned p0 = (unsigned)f2b(xn[0]) | ((unsigned)f2b(xn[1]) << 16);
      unsigned p1 = (unsigned)f2b(xn[2]) | ((unsigned)f2b(xn[3]) << 16);
      *reinterpret_cast<uint2*>(xb + (size_t)n * 64 + to * 4) = make_uint2(p0, p1);
    }
  }
  for (int p = t; p < 64 * 64; p += 256) {
    int i = p >> 6, o = p & 63;
    Bt[i * 200 + o] = b2[p];
  }
  __syncthreads();

  {
    float acc[2][4] = {{0, 0, 0, 0}, {0, 0, 0, 0}};
    for (int i = 0; i < 64; i++) {
      f32x2 a = *reinterpret_cast<const f32x2*>(&Ax[i * 34 + tn * 2]);
      f32x4 b = *reinterpret_cast<const f32x4*>(&Bt[i * 200 + to * 4]);
#pragma unroll
      for (int j = 0; j < 4; j++) {
        acc[0][j] += a[0] * b[j];
        acc[1][j] += a[1] * b[j];
      }
    }
#pragma unroll
    for (int nn = 0; nn < 2; nn++) {
      int n = n0 + tn * 2 + nn;
      if (n < NN)
        *reinterpret_cast<f32x4*>(xb2 + (size_t)n * 64 + to * 4) =
            *reinterpret_cast<f32x4*>(&acc[nn][0]);
    }
  }
}

// ---- fused Set2Set v2: 256 thr/graph, transposed weights, wave-parallel ---
__global__ __launch_bounds__(256) void k_s2s(const float* __restrict__ x,
                                             const int* __restrict__ batch,
                                             const float* __restrict__ WihT,
                                             const float* __restrict__ WhhT,
                                             const float* __restrict__ bih,
                                             const float* __restrict__ bhh,
                                             const float* __restrict__ W1T,
                                             const float* __restrict__ b1,
                                             const float* __restrict__ W2,
                                             const float* __restrict__ b2o,
                                             void* __restrict__ out,
                                             const int* __restrict__ flag) {
  const int b = blockIdx.x;
  const int t = threadIdx.x;
  const int lane = t & 63;
  const int w = t >> 6;
  int lo = 0, hi = NN;
  while (lo < hi) { int mid = (lo + hi) >> 1; if (batch[mid] < b) lo = mid + 1; else hi = mid; }
  const int ns = lo;
  hi = NN;
  while (lo < hi) { int mid = (lo + hi) >> 1; if (batch[mid] <= b) lo = mid + 1; else hi = mid; }
  const int cnt = lo - ns;

  __shared__ float hs[64], rs[64], cs[64], gs[256];
  __shared__ float es[512];
  __shared__ float red[4][64];
  __shared__ float wred[4], wsum[4];
  if (t < 64) { hs[t] = 0.0f; rs[t] = 0.0f; cs[t] = 0.0f; }
  __syncthreads();

  for (int step = 0; step < 3; step++) {
    // g[row=t] with coalesced transposed-weight loads
    float acc = bih[t] + bhh[t];
#pragma unroll 4
    for (int k = 0; k < 64; k++)
      acc += hs[k] * (WihT[k * 256 + t] + WhhT[k * 256 + t]);
#pragma unroll 4
    for (int k = 0; k < 64; k++)
      acc += rs[k] * WihT[(64 + k) * 256 + t];
    gs[t] = acc;
    __syncthreads();
    if (t < 64) {
      float ig = sigm(gs[t]), fg = sigm(gs[64 + t]);
      float gg = tanhf(gs[128 + t]), og = sigm(gs[192 + t]);
      float c = fg * cs[t] + ig * gg;
      cs[t] = c;
      hs[t] = og * tanhf(c);
    }
    __syncthreads();

    // e per node (one node per wave, strided by 4) + per-wave max
    float mxw = -3.4e38f;
    for (int j = w; j < cnt; j += 4) {
      float v = x[(size_t)(ns + j) * 64 + lane] * hs[lane];
#pragma unroll
      for (int mm = 32; mm; mm >>= 1) v += __shfl_xor(v, mm, 64);
      if (lane == 0 && j < 512) es[j] = v;
      mxw = fmaxf(mxw, v);
    }
    if (lane == 0) wred[w] = mxw;
    __syncthreads();
    float mx = fmaxf(fmaxf(wred[0], wred[1]), fmaxf(wred[2], wred[3]));

    // exp + total
    float ps = 0.0f;
    for (int i = t; i < cnt && i < 512; i += 256) {
      float a = __expf(es[i] - mx);
      es[i] = a;
      ps += a;
    }
#pragma unroll
    for (int mm = 32; mm; mm >>= 1) ps += __shfl_xor(ps, mm, 64);
    if (lane == 0) wsum[w] = ps;
    __syncthreads();
    float tot = wsum[0] + wsum[1] + wsum[2] + wsum[3];
    float inv = (cnt > 0) ? 1.0f / tot : 0.0f;

    // r = sum_j a_j * x_j  (wave-parallel over nodes, reduce in LDS)
    float pr = 0.0f;
    for (int j = w; j < cnt && j < 512; j += 4)
      pr += es[j] * x[(size_t)(ns + j) * 64 + lane];
    red[w][lane] = pr;
    __syncthreads();
    if (t < 64)
      rs[t] = (red[0][t] + red[1][t] + red[2][t] + red[3][t]) * inv;
    __syncthreads();
  }

  // out head (wave 0, coalesced W1T)
  if (t < 64) {
    float acc = b1[lane];
#pragma unroll 4
    for (int k = 0; k < 64; k++) acc += hs[k] * W1T[k * 64 + lane];
#pragma unroll 4
    for (int k = 0; k < 64; k++) acc += rs[k] * W1T[(64 + k) * 64 + lane];
    float u = siluf(acc) * W2[lane];
#pragma unroll
    for (int mm = 32; mm; mm >>= 1) u += __shfl_xor(u, mm, 64);
    if (lane == 0) {
      float v = u + b2o[0];
      if (*flag) ((unsigned short*)out)[b] = f2b(v);
      else ((float*)out)[b] = v;
    }
  }
}

// ---------------------------------------------------------------------------
template <int KC>
static void run_chunks(const unsigned short* xb, const unsigned short* W2t,
                       unsigned short* Tc, const unsigned short* s_bf,
                       const int* ei, float* m, hipStream_t stream) {
  const int nch = 128 / KC;
  for (int c = 0; c < nch; c++) {
    k_T<KC><<<dim3((NN + 127) / 128, (64 * KC) / 128), 256, 0, stream>>>(xb, W2t, Tc, c * KC);
    k_emsg<KC><<<EE / 4, 256, 0, stream>>>(Tc, s_bf, ei, m, c * KC, c == 0 ? 1 : 0);
  }
}

extern "C" void kernel_launch(void* const* d_in, const int* in_sizes, int n_in,
                              void* d_out, int out_size, void* d_ws, size_t ws_size,
                              hipStream_t stream) {
  (void)n_in; (void)out_size;
  const bool sig_order = (in_sizes[1] == 2 * EE);
  const void* p_x   = d_in[0];
  const void* p_ea  = sig_order ? d_in[2] : d_in[1];
  const void* p_pos = sig_order ? d_in[3] : d_in[2];
  const int* edge_index = (const int*)(sig_order ? d_in[1] : d_in[3]);
  const int* batch      = (const int*)d_in[4];
  const void* p_w[20];
  for (int i = 0; i < 20; i++) p_w[i] = d_in[5 + i];

  char* base = (char*)d_ws;
  size_t off = 0;
  auto alloc = [&](size_t bytes) -> char* {
    char* p = base + off;
    off = (off + bytes + 255) & ~(size_t)255;
    return p;
  };
  int* flag = (int*)alloc(4);
  static const int cvt_n[NCVT] = {
      64 * 11, 64, 128 * 5, 128, 4096 * 128, 4096,
      64 * 64, 64,
      192 * 64, 192 * 64, 192, 192,
      256 * 128, 256 * 64, 256, 256,
      64 * 128, 64, 64, 1};
  float* canon[NCVT];
  for (int i = 0; i < NCVT; i++) canon[i] = (float*)alloc((size_t)cvt_n[i] * 4);
  const float* c_flW  = canon[0];
  const float* c_flb  = canon[1];
  const float* c_W1   = canon[2];
  const float* c_b1   = canon[3];
  const float* c_W2   = canon[4];
  const float* c_b2   = canon[5];
  const float* c_rW   = canon[6];
  const float* c_rb   = canon[7];
  const float* c_gWih = canon[8];
  const float* c_gWhh = canon[9];
  const float* c_gbih = canon[10];
  const float* c_gbhh = canon[11];
  const float* c_lWih = canon[12];
  const float* c_lWhh = canon[13];
  const float* c_lbih = canon[14];
  const float* c_lbhh = canon[15];
  const float* c_oW1  = canon[16];
  const float* c_ob1  = canon[17];
  const float* c_oW2  = canon[18];
  const float* c_ob2  = canon[19];

  unsigned short* s_bf = (unsigned short*)alloc((size_t)EE * 128 * 2);
  float* m    = (float*)alloc((size_t)EE * 64 * 4);  // fallback only
  float* x    = (float*)alloc((size_t)NN * 64 * 4);
  unsigned short* xb = (unsigned short*)alloc((size_t)NN * 64 * 2);
  float* agg  = (float*)alloc((size_t)NN * 64 * 4);
  float* xb2  = (float*)alloc((size_t)NN * 64 * 4);
  unsigned short* W2t = (unsigned short*)alloc((size_t)4096 * 128 * 2);
  float* invd = (float*)alloc((size_t)NN * 4);
  int* cnt    = (int*)alloc((size_t)2 * NN * 4);
  int* cntd   = cnt + NN;
  int* eptr   = (int*)alloc((size_t)(NN + 1) * 4);
  int* cursor = (int*)alloc((size_t)NN * 4);
  int* eord   = (int*)alloc((size_t)EE * 4);
  float* WihT = (float*)alloc((size_t)128 * 256 * 4);
  float* WhhT = (float*)alloc((size_t)64 * 256 * 4);
  float* W1T  = (float*)alloc((size_t)128 * 64 * 4);
  size_t base_need = off;

  int KC = 0;
  const int kcs[5] = {128, 64, 32, 16, 8};
  for (int i = 0; i < 5; i++) {
    size_t need = base_need + (size_t)NN * 64 * kcs[i] * 2 + 256;
    if (need <= ws_size) { KC = kcs[i]; break; }
  }
  if (KC == 0) return;
  unsigned short* Tc = (unsigned short*)alloc((size_t)NN * 64 * KC * 2);

  // ---- dtype detect + weight convert + transposes ----
  k_detect<<<1, 256, 0, stream>>>((const unsigned*)p_ea, flag);
  Cvt cvt;
  for (int i = 0; i < 20; i++) cvt.src[i] = p_w[i];
  for (int i = 0; i < NCVT; i++) { cvt.dst[i] = canon[i]; cvt.n[i] = cvt_n[i]; }
  k_convert<<<512, 256, 0, stream>>>(cvt, flag);
  k_ltrans<<<224, 256, 0, stream>>>(c_lWih, c_lWhh, c_oW1, WihT, WhhT, W1T);

  // ---- prologue ----
  hipMemsetAsync(cnt, 0, (size_t)2 * NN * 4, stream);
  k_lift<<<NN / 4, 256, 0, stream>>>(p_x, c_flW, c_flb, c_b2, x, xb, xb2, agg, flag);
  k_sdeg<<<EE / 2, 256, 0, stream>>>(p_ea, p_pos, edge_index, c_W1, c_b1, s_bf, flag);
  k_w2t<<<(4096 * 128) / 256, 256, 0, stream>>>(c_W2, W2t);
  k_hist<<<(EE + 255) / 256, 256, 0, stream>>>(edge_index, cnt, cntd);
  k_scan<<<1, 256, 0, stream>>>(cnt, cntd, eptr, cursor, invd);
  k_scatter<<<(EE + 255) / 256, 256, 0, stream>>>(edge_index, cursor, eord);

  // ---- 4 message-passing layers ----
  for (int layer = 0; layer < 4; layer++) {
    if (KC == 128) {
      k_T<128><<<dim3((NN + 127) / 128, 64), 256, 0, stream>>>(xb, W2t, Tc, 0);
      k_group<<<NN / 4, 256, 0, stream>>>(Tc, s_bf, xb2, edge_index, eptr, eord, agg);
    } else {
      switch (KC) {
        case 64: run_chunks<64>(xb, W2t, Tc, s_bf, edge_index, m, stream); break;
        case 32: run_chunks<32>(xb, W2t, Tc, s_bf, edge_index, m, stream); break;
        case 16: run_chunks<16>(xb, W2t, Tc, s_bf, edge_index, m, stream); break;
        default: run_chunks<8>(xb, W2t, Tc, s_bf, edge_index, m, stream); break;
      }
      k_aggm<<<EE / 4, 256, 0, stream>>>(m, xb2, edge_index, agg);
    }
    k_xcgru<<<(NN + 31) / 32, 256, 0, stream>>>(x, xb, agg, invd, c_rW, c_rb,
                                                c_gWih, c_gWhh, c_gbih, c_gbhh,
                                                c_b2, xb2);
  }

  // ---- Set2Set + output head (one kernel, 4 waves/graph) ----
  k_s2s<<<BBG, 256, 0, stream>>>(x, batch, WihT, WhhT, c_lbih, c_lbhh,
                                 W1T, c_ob1, c_oW2, c_ob2, d_out, flag);
}